// Round 1
// baseline (9196.761 us; speedup 1.0000x reference)
//
#include <hip/hip_runtime.h>
#include <math.h>

#define B 256
#define L 256
#define H 512
#define H3 1536
#define TOKV 128
#define EOS_TOK 1
#define OUTC 257

__device__ __forceinline__ float dot4(float4 a, float4 b, float acc) {
    acc = fmaf(a.x, b.x, acc);
    acc = fmaf(a.y, b.y, acc);
    acc = fmaf(a.z, b.z, acc);
    acc = fmaf(a.w, b.w, acc);
    return acc;
}

__device__ __forceinline__ float sigmoidf_(float x) {
    return 1.0f / (1.0f + __expf(-x));
}

// h0[b][:] = stem_emb[stem[b]][:]
__global__ __launch_bounds__(256) void k_h0(const int* __restrict__ stem,
                                            const float* __restrict__ stem_emb,
                                            float* __restrict__ h0) {
    int idx = blockIdx.x * 256 + threadIdx.x;  // float4 id, total B*H/4 = 32768
    int b = idx >> 7;
    int c4 = idx & 127;
    const float4* src = (const float4*)(stem_emb + (size_t)stem[b] * H);
    ((float4*)(h0 + (size_t)b * H))[c4] = src[c4];
}

// gi_tok[v][j] = sum_c relu(token_emb[v][c]) * w_ih[j][c] + b_ih[j]
// grid: 8 (v-tiles of 16) * 16 (j-tiles of 96) = 128 blocks, 256 threads
__global__ __launch_bounds__(256) void k_gi_tok(
        const float* __restrict__ token_emb, const float* __restrict__ w_ih,
        const float* __restrict__ b_ih, float* __restrict__ gi_out) {
    __shared__ float wlds[96][132];
    __shared__ float elds[16][132];
    const int vi = blockIdx.x >> 4;
    const int ji = blockIdx.x & 15;
    const int v0 = vi << 4, j0 = ji * 96;
    const int tid = threadIdx.x;
    const int vl = tid & 7;
    const int jl = tid >> 3;
    float acc[2][3] = {{0.f, 0.f, 0.f}, {0.f, 0.f, 0.f}};
    for (int ck = 0; ck < 4; ++ck) {
        const int c0 = ck << 7;
        __syncthreads();
        for (int i = tid; i < 96 * 32; i += 256) {
            int row = i >> 5, c4 = i & 31;
            *(float4*)&wlds[row][c4 << 2] =
                *(const float4*)(w_ih + (size_t)(j0 + row) * H + c0 + (c4 << 2));
        }
        for (int i = tid; i < 16 * 32; i += 256) {
            int row = i >> 5, c4 = i & 31;
            float4 e = *(const float4*)(token_emb + (size_t)(v0 + row) * H + c0 + (c4 << 2));
            e.x = fmaxf(e.x, 0.f); e.y = fmaxf(e.y, 0.f);
            e.z = fmaxf(e.z, 0.f); e.w = fmaxf(e.w, 0.f);
            *(float4*)&elds[row][c4 << 2] = e;
        }
        __syncthreads();
        #pragma unroll 8
        for (int c = 0; c < 128; c += 4) {
            float4 wa = *(const float4*)&wlds[jl][c];
            float4 wb = *(const float4*)&wlds[32 + jl][c];
            float4 wc = *(const float4*)&wlds[64 + jl][c];
            float4 ea = *(const float4*)&elds[vl][c];
            float4 eb = *(const float4*)&elds[vl + 8][c];
            acc[0][0] = dot4(ea, wa, acc[0][0]);
            acc[0][1] = dot4(ea, wb, acc[0][1]);
            acc[0][2] = dot4(ea, wc, acc[0][2]);
            acc[1][0] = dot4(eb, wa, acc[1][0]);
            acc[1][1] = dot4(eb, wb, acc[1][1]);
            acc[1][2] = dot4(eb, wc, acc[1][2]);
        }
    }
    #pragma unroll
    for (int p = 0; p < 2; ++p) {
        int v = v0 + vl + (p << 3);
        #pragma unroll
        for (int s = 0; s < 3; ++s) {
            int j = j0 + (s << 5) + jl;
            gi_out[(size_t)v * H3 + j] = acc[p][s] + b_ih[j];
        }
    }
}

// One GRU step: h_out = GRUCell(h_in, x_t) with gi from gi_tok[goal[b][t]]
// (t < 0 means EOS token). grid: 16 b-tiles * 16 k-tiles = 256 blocks.
__global__ __launch_bounds__(256) void k_gru_step(
        const float* __restrict__ h_in, float* __restrict__ h_out,
        const float* __restrict__ w_hh, const float* __restrict__ b_hh,
        const float* __restrict__ gi_tok, const int* __restrict__ goal, int t) {
    __shared__ float wlds[96][132];
    __shared__ float hlds[16][132];
    const int bi = blockIdx.x >> 4;
    const int ki = blockIdx.x & 15;
    const int b0 = bi << 4, k0 = ki << 5;
    const int tid = threadIdx.x;
    const int bl = tid & 7;   // owns b0+bl and b0+bl+8
    const int kl = tid >> 3;  // 0..31
    float acc[2][3] = {{0.f, 0.f, 0.f}, {0.f, 0.f, 0.f}};
    for (int ck = 0; ck < 4; ++ck) {
        const int c0 = ck << 7;
        __syncthreads();
        for (int i = tid; i < 96 * 32; i += 256) {
            int row = i >> 5, c4 = i & 31;
            int g = row >> 5, kk = row & 31;
            *(float4*)&wlds[row][c4 << 2] =
                *(const float4*)(w_hh + (size_t)(g * H + k0 + kk) * H + c0 + (c4 << 2));
        }
        for (int i = tid; i < 16 * 32; i += 256) {
            int row = i >> 5, c4 = i & 31;
            *(float4*)&hlds[row][c4 << 2] =
                *(const float4*)(h_in + (size_t)(b0 + row) * H + c0 + (c4 << 2));
        }
        __syncthreads();
        #pragma unroll 8
        for (int c = 0; c < 128; c += 4) {
            float4 wr = *(const float4*)&wlds[kl][c];
            float4 wz = *(const float4*)&wlds[32 + kl][c];
            float4 wn = *(const float4*)&wlds[64 + kl][c];
            float4 ha = *(const float4*)&hlds[bl][c];
            float4 hb = *(const float4*)&hlds[bl + 8][c];
            acc[0][0] = dot4(ha, wr, acc[0][0]);
            acc[0][1] = dot4(ha, wz, acc[0][1]);
            acc[0][2] = dot4(ha, wn, acc[0][2]);
            acc[1][0] = dot4(hb, wr, acc[1][0]);
            acc[1][1] = dot4(hb, wz, acc[1][1]);
            acc[1][2] = dot4(hb, wn, acc[1][2]);
        }
    }
    const int kg = k0 + kl;
    const float bhr = b_hh[kg], bhz = b_hh[H + kg], bhn = b_hh[2 * H + kg];
    #pragma unroll
    for (int p = 0; p < 2; ++p) {
        const int bg = b0 + bl + (p << 3);
        const int v = (t >= 0) ? goal[(size_t)bg * L + t] : EOS_TOK;
        const float* gi = gi_tok + (size_t)v * H3;
        float r = sigmoidf_(gi[kg] + acc[p][0] + bhr);
        float z = sigmoidf_(gi[H + kg] + acc[p][1] + bhz);
        float n = tanhf(gi[2 * H + kg] + r * (acc[p][2] + bhn));
        float hp = h_in[(size_t)bg * H + kg];
        h_out[(size_t)bg * H + kg] = (1.f - z) * n + z * hp;
    }
}

// MLP over `nstates` stored states (contiguous, each B x H).
// Row (istate, b) -> out[b][col0 + istate]. 16 rows per block.
__global__ __launch_bounds__(256) void k_mlp(
        const float* __restrict__ states, int nstates,
        const float* __restrict__ w0, const float* __restrict__ b0,
        const float* __restrict__ w1, const float* __restrict__ b1,
        const float* __restrict__ w2, const float* __restrict__ b2,
        float* __restrict__ out, int col0) {
    __shared__ float ylds[16][516];  // y = relu(h); reused for v1 after layer 1
    __shared__ float wlds[32][132];
    __shared__ float red[16][33];
    const int tid = threadIdx.x;
    const int row0 = blockIdx.x << 4;
    const int istate = row0 >> 8;
    const int bbase = row0 & 255;
    const int rl = tid & 7;   // owns rows rl and rl+8
    const int jl = tid >> 3;  // 0..31
    (void)nstates;
    // stage y = relu(h rows)
    for (int i = tid; i < 16 * 128; i += 256) {
        int row = i >> 7, c4 = i & 127;
        float4 yv = *(const float4*)(states + (size_t)(row0 + row) * H + (c4 << 2));
        yv.x = fmaxf(yv.x, 0.f); yv.y = fmaxf(yv.y, 0.f);
        yv.z = fmaxf(yv.z, 0.f); yv.w = fmaxf(yv.w, 0.f);
        *(float4*)&ylds[row][c4 << 2] = yv;
    }
    // ---- layer 1: v1 = relu(y @ w0.T + b0), kept in registers ----
    float v1reg[16][2];
    for (int jt = 0; jt < 16; ++jt) {
        float a0 = 0.f, a1 = 0.f;
        for (int ck = 0; ck < 4; ++ck) {
            __syncthreads();
            for (int i = tid; i < 32 * 32; i += 256) {
                int row = i >> 5, c4 = i & 31;
                *(float4*)&wlds[row][c4 << 2] =
                    *(const float4*)(w0 + (size_t)((jt << 5) + row) * H + (ck << 7) + (c4 << 2));
            }
            __syncthreads();
            #pragma unroll 8
            for (int c = 0; c < 128; c += 4) {
                float4 wv = *(const float4*)&wlds[jl][c];
                float4 yA = *(const float4*)&ylds[rl][(ck << 7) + c];
                float4 yB = *(const float4*)&ylds[rl + 8][(ck << 7) + c];
                a0 = dot4(yA, wv, a0);
                a1 = dot4(yB, wv, a1);
            }
        }
        int j = (jt << 5) + jl;
        v1reg[jt][0] = fmaxf(a0 + b0[j], 0.f);
        v1reg[jt][1] = fmaxf(a1 + b0[j], 0.f);
    }
    // spill v1 into the (now dead) y buffer
    __syncthreads();
    #pragma unroll
    for (int jt = 0; jt < 16; ++jt) {
        int j = (jt << 5) + jl;
        ylds[rl][j] = v1reg[jt][0];
        ylds[rl + 8][j] = v1reg[jt][1];
    }
    // ---- layer 2 + dot with w2 ----
    float lik0 = 0.f, lik1 = 0.f;
    for (int jt = 0; jt < 16; ++jt) {
        float a0 = 0.f, a1 = 0.f;
        for (int ck = 0; ck < 4; ++ck) {
            __syncthreads();
            for (int i = tid; i < 32 * 32; i += 256) {
                int row = i >> 5, c4 = i & 31;
                *(float4*)&wlds[row][c4 << 2] =
                    *(const float4*)(w1 + (size_t)((jt << 5) + row) * H + (ck << 7) + (c4 << 2));
            }
            __syncthreads();
            #pragma unroll 8
            for (int c = 0; c < 128; c += 4) {
                float4 wv = *(const float4*)&wlds[jl][c];
                float4 yA = *(const float4*)&ylds[rl][(ck << 7) + c];
                float4 yB = *(const float4*)&ylds[rl + 8][(ck << 7) + c];
                a0 = dot4(yA, wv, a0);
                a1 = dot4(yB, wv, a1);
            }
        }
        int j = (jt << 5) + jl;
        lik0 += fmaxf(a0 + b1[j], 0.f) * w2[j];
        lik1 += fmaxf(a1 + b1[j], 0.f) * w2[j];
    }
    red[rl][jl] = lik0;
    red[rl + 8][jl] = lik1;
    __syncthreads();
    if (tid < 16) {
        float s = b2[0];
        #pragma unroll
        for (int q = 0; q < 32; ++q) s += red[tid][q];
        out[(size_t)(bbase + tid) * OUTC + col0 + istate] = s;
    }
}

extern "C" void kernel_launch(void* const* d_in, const int* in_sizes, int n_in,
                              void* d_out, int out_size, void* d_ws, size_t ws_size,
                              hipStream_t stream) {
    (void)in_sizes; (void)n_in; (void)out_size;
    const int* stem = (const int*)d_in[0];
    const int* goal = (const int*)d_in[1];
    const float* stem_emb = (const float*)d_in[2];
    const float* token_emb = (const float*)d_in[3];
    const float* w_ih = (const float*)d_in[4];
    const float* w_hh = (const float*)d_in[5];
    const float* b_ih = (const float*)d_in[6];
    const float* b_hh = (const float*)d_in[7];
    const float* w0 = (const float*)d_in[8];
    const float* b0 = (const float*)d_in[9];
    const float* w1 = (const float*)d_in[10];
    const float* b1 = (const float*)d_in[11];
    const float* w2 = (const float*)d_in[12];
    const float* b2 = (const float*)d_in[13];
    float* out = (float*)d_out;

    float* gi_tok = (float*)d_ws;
    float* hs = gi_tok + (size_t)TOKV * H3;
    const size_t slot = (size_t)B * H;

    // chunking: slots 0..Tc live in ws; full-size ws gives Tc = 256 (one chunk)
    size_t avail = ws_size / sizeof(float);
    long cap = 2;
    if (avail > (size_t)TOKV * H3 + 3 * slot) {
        cap = (long)((avail - (size_t)TOKV * H3) / slot) - 1;
    }
    int Tc = (int)(cap < 2 ? 2 : (cap > L ? L : cap));

    k_gi_tok<<<128, 256, 0, stream>>>(token_emb, w_ih, b_ih, gi_tok);
    k_h0<<<128, 256, 0, stream>>>(stem, stem_emb, hs);

    int t = 0;
    int cur = 0;  // slot index currently holding h_t
    while (t < L) {
        int steps = (L - t < Tc) ? (L - t) : Tc;
        for (int s = 0; s < steps; ++s) {
            const float* src = hs + (size_t)(s == 0 ? cur : s) * slot;
            k_gru_step<<<256, 256, 0, stream>>>(src, hs + (size_t)(s + 1) * slot,
                                                w_hh, b_hh, gi_tok, goal, t + s);
        }
        k_mlp<<<steps * 16, 256, 0, stream>>>(hs + slot, steps, w0, b0, w1, b1, w2, b2,
                                              out, t + 1);
        cur = steps;
        t += steps;
    }
    // EOS step: reads slot `cur`, writes slot 0 (h0 no longer needed)
    k_gru_step<<<256, 256, 0, stream>>>(hs + (size_t)cur * slot, hs,
                                        w_hh, b_hh, gi_tok, goal, -1);
    k_mlp<<<16, 256, 0, stream>>>(hs, 1, w0, b0, w1, b1, w2, b2, out, 0);
}

// Round 3
// 4212.711 us; speedup vs baseline: 2.1831x; 2.1831x over previous
//
#include <hip/hip_runtime.h>
#include <math.h>

#define B 256
#define L 256
#define H 512
#define H3 1536
#define TOKV 128
#define EOS_TOK 1
#define OUTC 257
#define SLOT ((size_t)B * H)   // floats per h-state

typedef short s16;
typedef s16 s16x8 __attribute__((ext_vector_type(8)));
typedef s16 s16x4 __attribute__((ext_vector_type(4)));
typedef float f32x4v __attribute__((ext_vector_type(4)));

__device__ __forceinline__ float sigmoidf_(float x) {
    return 1.0f / (1.0f + __expf(-x));
}

// fp32 -> bf16 bit pattern, round-to-nearest-even (same as (__bf16) cast)
__device__ __forceinline__ s16 f2bf(float x) {
    unsigned u = __builtin_bit_cast(unsigned, x);
    u += 0x7fffu + ((u >> 16) & 1u);
    return (s16)(u >> 16);
}
__device__ __forceinline__ float bf2f(s16 h) {
    return __builtin_bit_cast(float, ((unsigned)(unsigned short)h) << 16);
}

// ---------------- prep: elementwise split of a fp32 weight array ----------------
__global__ __launch_bounds__(256) void k_split(const float* __restrict__ src,
                                               s16* __restrict__ hi,
                                               s16* __restrict__ lo, int n4) {
    int i = blockIdx.x * 256 + threadIdx.x;
    if (i >= n4) return;
    float4 x = ((const float4*)src)[i];
    float xs[4] = {x.x, x.y, x.z, x.w};
    s16x4 h, l;
    #pragma unroll
    for (int q = 0; q < 4; ++q) {
        s16 hh = f2bf(xs[q]);
        h[q] = hh;
        l[q] = f2bf(xs[q] - bf2f(hh));
    }
    *(s16x4*)(hi + (size_t)i * 4) = h;
    *(s16x4*)(lo + (size_t)i * 4) = l;
}

// ---------------- prep: h0 gather -> hs[0] fp32 + split ping buffer ----------------
__global__ __launch_bounds__(256) void k_h0(const int* __restrict__ stem,
                                            const float* __restrict__ stem_emb,
                                            float* __restrict__ h0,
                                            s16* __restrict__ sh,
                                            s16* __restrict__ sl) {
    int idx = blockIdx.x * 256 + threadIdx.x;  // float4 id, total B*H/4 = 32768
    int b = idx >> 7;
    int c4 = idx & 127;
    float4 v = ((const float4*)(stem_emb + (size_t)stem[b] * H))[c4];
    ((float4*)(h0 + (size_t)b * H))[c4] = v;
    float xs[4] = {v.x, v.y, v.z, v.w};
    s16x4 h, l;
    #pragma unroll
    for (int q = 0; q < 4; ++q) {
        s16 hh = f2bf(xs[q]);
        h[q] = hh;
        l[q] = f2bf(xs[q] - bf2f(hh));
    }
    *(s16x4*)(sh + (size_t)b * H + c4 * 4) = h;
    *(s16x4*)(sl + (size_t)b * H + c4 * 4) = l;
}

// ---------------- prep: gi_tok[v][j] = relu(token_emb[v]) . w_ih[j] + b_ih[j] (fp32) ----------------
__global__ __launch_bounds__(256) void k_gi_tok(
        const float* __restrict__ token_emb, const float* __restrict__ w_ih,
        const float* __restrict__ b_ih, float* __restrict__ gi_out) {
    __shared__ float wlds[96][132];
    __shared__ float elds[16][132];
    const int vi = blockIdx.x >> 4;
    const int ji = blockIdx.x & 15;
    const int v0 = vi << 4, j0 = ji * 96;
    const int tid = threadIdx.x;
    const int vl = tid & 7;
    const int jl = tid >> 3;
    float acc[2][3] = {{0.f, 0.f, 0.f}, {0.f, 0.f, 0.f}};
    for (int ck = 0; ck < 4; ++ck) {
        const int c0 = ck << 7;
        __syncthreads();
        for (int i = tid; i < 96 * 32; i += 256) {
            int row = i >> 5, c4 = i & 31;
            *(float4*)&wlds[row][c4 << 2] =
                *(const float4*)(w_ih + (size_t)(j0 + row) * H + c0 + (c4 << 2));
        }
        for (int i = tid; i < 16 * 32; i += 256) {
            int row = i >> 5, c4 = i & 31;
            float4 e = *(const float4*)(token_emb + (size_t)(v0 + row) * H + c0 + (c4 << 2));
            e.x = fmaxf(e.x, 0.f); e.y = fmaxf(e.y, 0.f);
            e.z = fmaxf(e.z, 0.f); e.w = fmaxf(e.w, 0.f);
            *(float4*)&elds[row][c4 << 2] = e;
        }
        __syncthreads();
        #pragma unroll 8
        for (int c = 0; c < 128; c += 4) {
            float4 wa = *(const float4*)&wlds[jl][c];
            float4 wb = *(const float4*)&wlds[32 + jl][c];
            float4 wc = *(const float4*)&wlds[64 + jl][c];
            float4 ea = *(const float4*)&elds[vl][c];
            float4 eb = *(const float4*)&elds[vl + 8][c];
            acc[0][0] += ea.x*wa.x + ea.y*wa.y + ea.z*wa.z + ea.w*wa.w;
            acc[0][1] += ea.x*wb.x + ea.y*wb.y + ea.z*wb.z + ea.w*wb.w;
            acc[0][2] += ea.x*wc.x + ea.y*wc.y + ea.z*wc.z + ea.w*wc.w;
            acc[1][0] += eb.x*wa.x + eb.y*wa.y + eb.z*wa.z + eb.w*wa.w;
            acc[1][1] += eb.x*wb.x + eb.y*wb.y + eb.z*wb.z + eb.w*wb.w;
            acc[1][2] += eb.x*wc.x + eb.y*wc.y + eb.z*wc.z + eb.w*wc.w;
        }
    }
    #pragma unroll
    for (int p = 0; p < 2; ++p) {
        int v = v0 + vl + (p << 3);
        #pragma unroll
        for (int s = 0; s < 3; ++s) {
            int j = j0 + (s << 5) + jl;
            gi_out[(size_t)v * H3 + j] = acc[p][s] + b_ih[j];
        }
    }
}

// ---------------- GRU step via MFMA (split-bf16, 3-term) ----------------
// grid: 512 blocks x 64 thr. block = (mt 0..15) x (jt 0..31).
// Wave computes GH[b in mt*16..+16][j in jt*16..+16] for all 3 gates, then the
// fused gate epilogue. t < 0 = EOS token.
__global__ __launch_bounds__(64) void k_gru_mfma(
        const s16* __restrict__ h_hi, const s16* __restrict__ h_lo,
        s16* __restrict__ o_hi, s16* __restrict__ o_lo,
        const s16* __restrict__ w_hi, const s16* __restrict__ w_lo,
        const float* __restrict__ b_hh, const float* __restrict__ gi_tok,
        const int* __restrict__ goal, const float* __restrict__ hp_src,
        float* __restrict__ h_out, int t) {
    const int l = threadIdx.x;
    const int mt = blockIdx.x >> 5;
    const int jt = blockIdx.x & 31;
    const int ln = l & 15;
    const int kg = l >> 4;
    const int row = mt * 16 + ln;   // batch row this lane loads A for
    const int j = jt * 16 + ln;     // gate column this lane owns in C

    const s16* ah = h_hi + (size_t)row * H + kg * 8;
    const s16* al = h_lo + (size_t)row * H + kg * 8;
    const s16* wrh = w_hi + (size_t)j * H + kg * 8;
    const s16* wrl = w_lo + (size_t)j * H + kg * 8;
    const s16* wzh = wrh + (size_t)H * H;
    const s16* wzl = wrl + (size_t)H * H;
    const s16* wnh = wzh + (size_t)H * H;
    const s16* wnl = wzl + (size_t)H * H;

    f32x4v ar{}, az{}, an{};
    #pragma unroll 4
    for (int kc = 0; kc < H; kc += 32) {
        s16x8 Ah = *(const s16x8*)(ah + kc);
        s16x8 Al = *(const s16x8*)(al + kc);
        s16x8 Rh = *(const s16x8*)(wrh + kc);
        s16x8 Rl = *(const s16x8*)(wrl + kc);
        s16x8 Zh = *(const s16x8*)(wzh + kc);
        s16x8 Zl = *(const s16x8*)(wzl + kc);
        s16x8 Nh = *(const s16x8*)(wnh + kc);
        s16x8 Nl = *(const s16x8*)(wnl + kc);
        ar = __builtin_amdgcn_mfma_f32_16x16x32_bf16(Ah, Rh, ar, 0, 0, 0);
        az = __builtin_amdgcn_mfma_f32_16x16x32_bf16(Ah, Zh, az, 0, 0, 0);
        an = __builtin_amdgcn_mfma_f32_16x16x32_bf16(Ah, Nh, an, 0, 0, 0);
        ar = __builtin_amdgcn_mfma_f32_16x16x32_bf16(Ah, Rl, ar, 0, 0, 0);
        az = __builtin_amdgcn_mfma_f32_16x16x32_bf16(Ah, Zl, az, 0, 0, 0);
        an = __builtin_amdgcn_mfma_f32_16x16x32_bf16(Ah, Nl, an, 0, 0, 0);
        ar = __builtin_amdgcn_mfma_f32_16x16x32_bf16(Al, Rh, ar, 0, 0, 0);
        az = __builtin_amdgcn_mfma_f32_16x16x32_bf16(Al, Zh, az, 0, 0, 0);
        an = __builtin_amdgcn_mfma_f32_16x16x32_bf16(Al, Nh, an, 0, 0, 0);
    }

    const float bhr = b_hh[j], bhz = b_hh[H + j], bhn = b_hh[2 * H + j];
    #pragma unroll
    for (int q = 0; q < 4; ++q) {
        const int b = mt * 16 + kg * 4 + q;   // C row = (l>>4)*4 + q
        const int v = (t >= 0) ? goal[(size_t)b * L + t] : EOS_TOK;
        const float* gi = gi_tok + (size_t)v * H3;
        float r = sigmoidf_(gi[j] + ar[q] + bhr);
        float z = sigmoidf_(gi[H + j] + az[q] + bhz);
        float nn = tanhf(gi[2 * H + j] + r * (an[q] + bhn));
        float hp = hp_src[(size_t)b * H + j];
        float hn = (1.f - z) * nn + z * hp;
        h_out[(size_t)b * H + j] = hn;
        s16 hb = f2bf(hn);
        o_hi[(size_t)b * H + j] = hb;
        o_lo[(size_t)b * H + j] = f2bf(hn - bf2f(hb));
    }
}

// ---------------- fused MLP via MFMA ----------------
// 64 rows per block (rows = slot*256 + b over the chunk), 4 waves, wave w owns
// n in [w*128, w*128+128). v1 lives in LDS fp32 with XOR swizzle.
__global__ __launch_bounds__(256, 1) void k_mlp_mfma(
        const float* __restrict__ states,
        const s16* __restrict__ w0h, const s16* __restrict__ w0l,
        const float* __restrict__ b0v,
        const s16* __restrict__ w1h, const s16* __restrict__ w1l,
        const float* __restrict__ b1v,
        const float* __restrict__ w2v, const float* __restrict__ b2v,
        float* __restrict__ out, int col0) {
    __shared__ float v1s[64 * 512];   // 128 KB
    __shared__ float red[4][64];
    const int tid = threadIdx.x;
    const int wid = tid >> 6;
    const int l = tid & 63;
    const int ln = l & 15;
    const int kg = l >> 4;
    const int r0 = blockIdx.x * 64;
    const int col = col0 + (r0 >> 8);
    const int b0 = r0 & 255;

    f32x4v acc[4][8];
    #pragma unroll
    for (int mf = 0; mf < 4; ++mf)
        #pragma unroll
        for (int nf = 0; nf < 8; ++nf) acc[mf][nf] = f32x4v{};

    // ---- GEMM1: v1 = relu(relu(h) @ w0.T + b0) ----
    for (int kc = 0; kc < H; kc += 32) {
        s16x8 Ah[4], Al[4];
        #pragma unroll
        for (int mf = 0; mf < 4; ++mf) {
            const float* ap = states + (size_t)(r0 + mf * 16 + ln) * H + kc + kg * 8;
            float4 x0 = *(const float4*)ap;
            float4 x1 = *(const float4*)(ap + 4);
            float y[8] = {fmaxf(x0.x,0.f), fmaxf(x0.y,0.f), fmaxf(x0.z,0.f), fmaxf(x0.w,0.f),
                          fmaxf(x1.x,0.f), fmaxf(x1.y,0.f), fmaxf(x1.z,0.f), fmaxf(x1.w,0.f)};
            #pragma unroll
            for (int i = 0; i < 8; ++i) {
                s16 hh = f2bf(y[i]);
                Ah[mf][i] = hh;
                Al[mf][i] = f2bf(y[i] - bf2f(hh));
            }
        }
        #pragma unroll
        for (int nf = 0; nf < 8; ++nf) {
            const int n = wid * 128 + nf * 16 + ln;
            s16x8 Bh = *(const s16x8*)(w0h + (size_t)n * H + kc + kg * 8);
            s16x8 Bl = *(const s16x8*)(w0l + (size_t)n * H + kc + kg * 8);
            #pragma unroll
            for (int mf = 0; mf < 4; ++mf) {
                acc[mf][nf] = __builtin_amdgcn_mfma_f32_16x16x32_bf16(Ah[mf], Bh, acc[mf][nf], 0, 0, 0);
                acc[mf][nf] = __builtin_amdgcn_mfma_f32_16x16x32_bf16(Ah[mf], Bl, acc[mf][nf], 0, 0, 0);
                acc[mf][nf] = __builtin_amdgcn_mfma_f32_16x16x32_bf16(Al[mf], Bh, acc[mf][nf], 0, 0, 0);
            }
        }
    }
    float bn[8];
    #pragma unroll
    for (int nf = 0; nf < 8; ++nf) bn[nf] = b0v[wid * 128 + nf * 16 + ln];
    #pragma unroll
    for (int mf = 0; mf < 4; ++mf)
        #pragma unroll
        for (int nf = 0; nf < 8; ++nf)
            #pragma unroll
            for (int q = 0; q < 4; ++q) {
                int m = mf * 16 + kg * 4 + q;
                int n = wid * 128 + nf * 16 + ln;
                v1s[m * 512 + (n ^ ((m & 7) << 2))] = fmaxf(acc[mf][nf][q] + bn[nf], 0.f);
            }
    __syncthreads();

    // ---- GEMM2: v2 = relu(v1 @ w1.T + b1); lik = v2 . w2 ----
    #pragma unroll
    for (int mf = 0; mf < 4; ++mf)
        #pragma unroll
        for (int nf = 0; nf < 8; ++nf) acc[mf][nf] = f32x4v{};
    for (int kc = 0; kc < H; kc += 32) {
        s16x8 Ah[4], Al[4];
        #pragma unroll
        for (int mf = 0; mf < 4; ++mf) {
            const int rr = mf * 16 + ln;
            const int c = (rr & 7) << 2;
            const int k0 = kc + kg * 8;
            float4 y0 = *(const float4*)(v1s + rr * 512 + (k0 ^ c));
            float4 y1 = *(const float4*)(v1s + rr * 512 + ((k0 + 4) ^ c));
            float y[8] = {y0.x, y0.y, y0.z, y0.w, y1.x, y1.y, y1.z, y1.w};
            #pragma unroll
            for (int i = 0; i < 8; ++i) {
                s16 hh = f2bf(y[i]);
                Ah[mf][i] = hh;
                Al[mf][i] = f2bf(y[i] - bf2f(hh));
            }
        }
        #pragma unroll
        for (int nf = 0; nf < 8; ++nf) {
            const int n = wid * 128 + nf * 16 + ln;
            s16x8 Bh = *(const s16x8*)(w1h + (size_t)n * H + kc + kg * 8);
            s16x8 Bl = *(const s16x8*)(w1l + (size_t)n * H + kc + kg * 8);
            #pragma unroll
            for (int mf = 0; mf < 4; ++mf) {
                acc[mf][nf] = __builtin_amdgcn_mfma_f32_16x16x32_bf16(Ah[mf], Bh, acc[mf][nf], 0, 0, 0);
                acc[mf][nf] = __builtin_amdgcn_mfma_f32_16x16x32_bf16(Ah[mf], Bl, acc[mf][nf], 0, 0, 0);
                acc[mf][nf] = __builtin_amdgcn_mfma_f32_16x16x32_bf16(Al[mf], Bh, acc[mf][nf], 0, 0, 0);
            }
        }
    }
    float b1n[8], w2n[8];
    #pragma unroll
    for (int nf = 0; nf < 8; ++nf) {
        int n = wid * 128 + nf * 16 + ln;
        b1n[nf] = b1v[n];
        w2n[nf] = w2v[n];
    }
    float psum[4][4];
    #pragma unroll
    for (int mf = 0; mf < 4; ++mf)
        #pragma unroll
        for (int q = 0; q < 4; ++q) {
            float s = 0.f;
            #pragma unroll
            for (int nf = 0; nf < 8; ++nf)
                s += fmaxf(acc[mf][nf][q] + b1n[nf], 0.f) * w2n[nf];
            psum[mf][q] = s;
        }
    #pragma unroll
    for (int mf = 0; mf < 4; ++mf)
        #pragma unroll
        for (int q = 0; q < 4; ++q) {
            float s = psum[mf][q];
            #pragma unroll
            for (int msk = 1; msk < 16; msk <<= 1)
                s += __shfl_xor(s, msk, 64);
            psum[mf][q] = s;
        }
    if (ln == 0) {
        #pragma unroll
        for (int mf = 0; mf < 4; ++mf)
            #pragma unroll
            for (int q = 0; q < 4; ++q)
                red[wid][mf * 16 + kg * 4 + q] = psum[mf][q];
    }
    __syncthreads();
    if (tid < 64) {
        float s = b2v[0] + red[0][tid] + red[1][tid] + red[2][tid] + red[3][tid];
        out[(size_t)(b0 + tid) * OUTC + col] = s;
    }
}

extern "C" void kernel_launch(void* const* d_in, const int* in_sizes, int n_in,
                              void* d_out, int out_size, void* d_ws, size_t ws_size,
                              hipStream_t stream) {
    (void)in_sizes; (void)n_in; (void)out_size;
    const int* stem = (const int*)d_in[0];
    const int* goal = (const int*)d_in[1];
    const float* stem_emb = (const float*)d_in[2];
    const float* token_emb = (const float*)d_in[3];
    const float* w_ih = (const float*)d_in[4];
    const float* w_hh = (const float*)d_in[5];
    const float* b_ih = (const float*)d_in[6];
    const float* b_hh = (const float*)d_in[7];
    const float* w0 = (const float*)d_in[8];
    const float* b0 = (const float*)d_in[9];
    const float* w1 = (const float*)d_in[10];
    const float* b1 = (const float*)d_in[11];
    const float* w2 = (const float*)d_in[12];
    const float* b2 = (const float*)d_in[13];
    float* out = (float*)d_out;

    char* p = (char*)d_ws;
    float* gi_tok = (float*)p;      p += (size_t)TOKV * H3 * 4;
    s16* whh_h = (s16*)p;           p += (size_t)H3 * H * 2;
    s16* whh_l = (s16*)p;           p += (size_t)H3 * H * 2;
    s16* w0h = (s16*)p;             p += (size_t)H * H * 2;
    s16* w0l = (s16*)p;             p += (size_t)H * H * 2;
    s16* w1h = (s16*)p;             p += (size_t)H * H * 2;
    s16* w1l = (s16*)p;             p += (size_t)H * H * 2;
    s16 *sph[2], *spl[2];
    sph[0] = (s16*)p;               p += SLOT * 2;
    spl[0] = (s16*)p;               p += SLOT * 2;
    sph[1] = (s16*)p;               p += SLOT * 2;
    spl[1] = (s16*)p;               p += SLOT * 2;
    float* hs = (float*)p;
    size_t used = (size_t)(p - (char*)d_ws);
    long slots = (long)((ws_size - used) / (SLOT * 4));
    long cap = slots - 1;
    int Tc = (int)(cap < 2 ? 2 : (cap > L ? L : cap));

    // prep
    k_split<<<768, 256, 0, stream>>>(w_hh, whh_h, whh_l, H3 * H / 4);
    k_split<<<256, 256, 0, stream>>>(w0, w0h, w0l, H * H / 4);
    k_split<<<256, 256, 0, stream>>>(w1, w1h, w1l, H * H / 4);
    k_gi_tok<<<128, 256, 0, stream>>>(token_emb, w_ih, b_ih, gi_tok);
    k_h0<<<128, 256, 0, stream>>>(stem, stem_emb, hs, sph[0], spl[0]);

    int t = 0;
    int cur = 0;
    while (t < L) {
        int steps = (L - t < Tc) ? (L - t) : Tc;
        for (int s = 0; s < steps; ++s) {
            int tg = t + s;
            const float* hp = hs + (size_t)(s == 0 ? cur : s) * SLOT;
            k_gru_mfma<<<512, 64, 0, stream>>>(
                sph[tg & 1], spl[tg & 1], sph[(tg + 1) & 1], spl[(tg + 1) & 1],
                whh_h, whh_l, b_hh, gi_tok, goal, hp,
                hs + (size_t)(s + 1) * SLOT, tg);
        }
        k_mlp_mfma<<<steps * 4, 256, 0, stream>>>(hs + SLOT, w0h, w0l, b0,
                                                  w1h, w1l, b1, w2, b2, out, t + 1);
        cur = steps;
        t += steps;
    }
    // EOS step: reads split parity 0 (t=256 even), writes hs slot 0
    k_gru_mfma<<<512, 64, 0, stream>>>(sph[0], spl[0], sph[1], spl[1],
                                       whh_h, whh_l, b_hh, gi_tok, goal,
                                       hs + (size_t)cur * SLOT, hs, -1);
    k_mlp_mfma<<<4, 256, 0, stream>>>(hs, w0h, w0l, b0, w1h, w1l, b1, w2, b2, out, 0);
}